// Round 5
// baseline (86.350 us; speedup 1.0000x reference)
//
#include <hip/hip_runtime.h>

// pose3d_calibration: B=262144 poses, J=15.
// out[0] = mean_{B,6} (|bone_l|^2 - |bone_r|^2)^2        (f32 path: |err|~1e-6)
// out[1] = mean_{B,2,15} (project(R^T (X - C)) - pose2d)^2 (f64 path: bit-matches np)
//
// R5: single FUSED kernel. Per-thread float4 register loads (R4), then
// last-block-ticket final reduction (saves the 1-block finish dispatch+gap).
// Counter zeroed per call via hipMemsetAsync (stream-ordered, capture-legal).
// Cross-XCD correctness: partials and ticket use agent-scope atomics.
// VGPR trim: all storage f32; f64 only transiently inside the joint loop.

typedef float f4u __attribute__((ext_vector_type(4), aligned(4)));
typedef float f2u __attribute__((ext_vector_type(2), aligned(4)));

__global__ __launch_bounds__(256) void pose_calib_fused(
    const float* __restrict__ pose3d,   // (B,3,15)
    const float* __restrict__ pose2d,   // (B,2,15)
    const float* __restrict__ Rd,       // (B,3,3)
    const float* __restrict__ Cd,       // (B,3,1)
    double* __restrict__ part,          // (nblk,2) in d_ws
    unsigned* __restrict__ cnt,         // ticket counter in d_ws (pre-zeroed)
    float* __restrict__ out,
    int B, int nblk, double inv_n_sym, double inv_n_proj)
{
    const int p = blockIdx.x * 256 + threadIdx.x;
    float  sym_f  = 0.0f;
    double proj_d = 0.0;

    if (p < B) {
        const float* g3 = pose3d + (size_t)p * 45;
        const float* g2 = pose2d + (size_t)p * 30;
        const float* gR = Rd + (size_t)p * 9;
        const float* gC = Cd + (size_t)p * 3;

        // ---- issue all loads first (wide, dword-aligned) ----
        float X[45], P2a[30], Rr[9], Cc[3];
        #pragma unroll
        for (int k = 0; k < 11; ++k) {
            f4u v = *(const f4u*)(g3 + 4 * k);
            X[4*k] = v.x; X[4*k+1] = v.y; X[4*k+2] = v.z; X[4*k+3] = v.w;
        }
        X[44] = g3[44];
        #pragma unroll
        for (int k = 0; k < 7; ++k) {
            f4u v = *(const f4u*)(g2 + 4 * k);
            P2a[4*k] = v.x; P2a[4*k+1] = v.y; P2a[4*k+2] = v.z; P2a[4*k+3] = v.w;
        }
        { f2u v = *(const f2u*)(g2 + 28); P2a[28] = v.x; P2a[29] = v.y; }
        { f4u v = *(const f4u*)(gR);     Rr[0]=v.x; Rr[1]=v.y; Rr[2]=v.z; Rr[3]=v.w; }
        { f4u v = *(const f4u*)(gR + 4); Rr[4]=v.x; Rr[5]=v.y; Rr[6]=v.z; Rr[7]=v.w; }
        Rr[8] = gR[8];
        { f2u v = *(const f2u*)(gC); Cc[0] = v.x; Cc[1] = v.y; }
        Cc[2] = gC[2];

        // ---- bone symmetry (f32; |err| ~1e-6 << 1.57e6 threshold) ----
        const int lb0[6] = {1,5,6,14,11,12}, lb1[6] = {5,6,7,11,12,13};
        const int rb0[6] = {1,2,3,14,8,9},   rb1[6] = {2,3,4,8,9,10};
        #pragma unroll
        for (int k = 0; k < 6; ++k) {
            float ll = 0.f, lr = 0.f;
            #pragma unroll
            for (int c = 0; c < 3; ++c) {
                float dl = X[c*15 + lb0[k]] - X[c*15 + lb1[k]];
                float dr = X[c*15 + rb0[k]] - X[c*15 + rb1[k]];
                ll += dl * dl;
                lr += dr * dr;
            }
            float d = ll - lr;
            sym_f += d * d;
        }

        // ---- projection (f64 transients only; storage stays f32) ----
        #pragma unroll
        for (int j = 0; j < 15; ++j) {
            double q0 = (double)X[j]      - (double)Cc[0];
            double q1 = (double)X[15 + j] - (double)Cc[1];
            double q2 = (double)X[30 + j] - (double)Cc[2];
            double P0 = (double)Rr[0]*q0 + (double)Rr[3]*q1 + (double)Rr[6]*q2;
            double P1 = (double)Rr[1]*q0 + (double)Rr[4]*q1 + (double)Rr[7]*q2;
            double Pz = (double)Rr[2]*q0 + (double)Rr[5]*q1 + (double)Rr[8]*q2;
            double rz = 1.0 / Pz;
            double du = 512.0 * P0 * rz + 512.0 - (double)P2a[j];
            double dv = 512.0 * P1 * rz + 256.0 - (double)P2a[15 + j];
            proj_d += du * du + dv * dv;
        }
    }

    // ---- block reduction: wave shfl -> LDS across 4 waves ----
    double sym_d = (double)sym_f;
    #pragma unroll
    for (int off = 32; off > 0; off >>= 1) {
        sym_d  += __shfl_down(sym_d,  off, 64);
        proj_d += __shfl_down(proj_d, off, 64);
    }
    __shared__ double s_sym[4], s_proj[4];
    __shared__ int amLast;
    const int lane = threadIdx.x & 63;
    const int wid  = threadIdx.x >> 6;
    if (lane == 0) { s_sym[wid] = sym_d; s_proj[wid] = proj_d; }
    __syncthreads();

    // ---- publish partial + take ticket (agent scope: cross-XCD safe) ----
    if (threadIdx.x == 0) {
        double sd = s_sym[0] + s_sym[1] + s_sym[2] + s_sym[3];
        double pd = s_proj[0] + s_proj[1] + s_proj[2] + s_proj[3];
        __hip_atomic_store(&part[2*(size_t)blockIdx.x],     sd,
                           __ATOMIC_RELEASE, __HIP_MEMORY_SCOPE_AGENT);
        __hip_atomic_store(&part[2*(size_t)blockIdx.x + 1], pd,
                           __ATOMIC_RELEASE, __HIP_MEMORY_SCOPE_AGENT);
        unsigned old = __hip_atomic_fetch_add(cnt, 1u,
                           __ATOMIC_ACQ_REL, __HIP_MEMORY_SCOPE_AGENT);
        amLast = (old == (unsigned)nblk - 1);
    }
    __syncthreads();
    if (!amLast) return;

    // ---- last block: final reduction over all partials ----
    double ss = 0.0, pp = 0.0;
    for (int i = threadIdx.x; i < nblk; i += 256) {
        ss += __hip_atomic_load(&part[2*(size_t)i],
                                __ATOMIC_RELAXED, __HIP_MEMORY_SCOPE_AGENT);
        pp += __hip_atomic_load(&part[2*(size_t)i + 1],
                                __ATOMIC_RELAXED, __HIP_MEMORY_SCOPE_AGENT);
    }
    #pragma unroll
    for (int off = 32; off > 0; off >>= 1) {
        ss += __shfl_down(ss, off, 64);
        pp += __shfl_down(pp, off, 64);
    }
    __syncthreads();   // s_sym/s_proj reuse
    if (lane == 0) { s_sym[wid] = ss; s_proj[wid] = pp; }
    __syncthreads();
    if (threadIdx.x == 0) {
        double S = s_sym[0] + s_sym[1] + s_sym[2] + s_sym[3];
        double P = s_proj[0] + s_proj[1] + s_proj[2] + s_proj[3];
        out[0] = (float)(S * inv_n_sym);
        out[1] = (float)(P * inv_n_proj);
    }
}

extern "C" void kernel_launch(void* const* d_in, const int* in_sizes, int n_in,
                              void* d_out, int out_size, void* d_ws, size_t ws_size,
                              hipStream_t stream) {
    const float* pose3d = (const float*)d_in[0];
    const float* pose2d = (const float*)d_in[1];
    const float* Rd     = (const float*)d_in[2];
    const float* Cd     = (const float*)d_in[3];

    const int B    = in_sizes[3] / 3;          // C_drone is (B,3,1)
    const int nblk = (B + 255) / 256;          // 1024 @ B=262144

    double*   part = (double*)d_ws;                          // nblk*2 doubles
    unsigned* cnt  = (unsigned*)((char*)d_ws + (size_t)nblk * 2 * sizeof(double));

    // ticket counter must be 0 at kernel entry, every call (d_ws is poisoned
    // 0xAA once before timing and never re-poisoned between replays).
    hipMemsetAsync(cnt, 0, sizeof(unsigned), stream);

    pose_calib_fused<<<nblk, 256, 0, stream>>>(
        pose3d, pose2d, Rd, Cd, part, cnt, (float*)d_out,
        B, nblk, 1.0 / ((double)B * 6.0), 1.0 / ((double)B * 30.0));
}

// Round 6
// 64.001 us; speedup vs baseline: 1.3492x; 1.3492x over previous
//
#include <hip/hip_runtime.h>

// pose3d_calibration: B=262144 poses, J=15.
// out[0] = mean_{B,6} (|bone_l|^2 - |bone_r|^2)^2
// out[1] = mean_{B,2,15} (project(R^T (X - C)) - pose2d)^2
//
// R6: R4's measured-good body VERBATIM (22.45us total as 2 kernels).
// Single change: epilogue fuses the final reduction via 2 pre-scaled f64
// hardware atomicAdds (global_atomic_add_f64, device-scope) + threadfence +
// ticket; last block casts to out. Saves the 1-block finish dispatch + gap.
// R5 post-mortem: its 121us came with VGPR 64 + VALUBusy 4% + no HBM traffic
// -> body restructure broke register residency; so the body here is untouched.

typedef float f4u __attribute__((ext_vector_type(4), aligned(4)));
typedef float f2u __attribute__((ext_vector_type(2), aligned(4)));

__global__ __launch_bounds__(256) void pose_calib_main(
    const float* __restrict__ pose3d,   // (B,3,15)
    const float* __restrict__ pose2d,   // (B,2,15)
    const float* __restrict__ Rd,       // (B,3,3)
    const float* __restrict__ Cd,       // (B,3,1)
    double* __restrict__ acc,           // d_ws: acc[0..1] (pre-zeroed)
    unsigned* __restrict__ cnt,         // d_ws: ticket (pre-zeroed)
    float* __restrict__ out,
    int B, int nblk, double inv_n_sym, double inv_n_proj)
{
    const int p = blockIdx.x * 256 + threadIdx.x;
    double sym_d = 0.0, proj_d = 0.0;

    if (p < B) {
        const float* g3 = pose3d + (size_t)p * 45;
        const float* g2 = pose2d + (size_t)p * 30;
        const float* gR = Rd + (size_t)p * 9;
        const float* gC = Cd + (size_t)p * 3;

        // ---- issue all loads first (wide, 4B-aligned) ----
        float X[45], pu[15], pv[15], Rr[9], Cc[3];
        #pragma unroll
        for (int k = 0; k < 11; ++k) {
            f4u v = *(const f4u*)(g3 + 4 * k);
            X[4 * k] = v.x; X[4 * k + 1] = v.y; X[4 * k + 2] = v.z; X[4 * k + 3] = v.w;
        }
        X[44] = g3[44];
        #pragma unroll
        for (int k = 0; k < 7; ++k) {
            f4u v = *(const f4u*)(g2 + 4 * k);
            float* d = (k < 4) ? &pu[4 * k] : &pv[4 * k - 15];
            // avoid dynamic pointer games; just index directly:
            (void)d;
            int base = 4 * k;
            float vals[4] = {v.x, v.y, v.z, v.w};
            #pragma unroll
            for (int t = 0; t < 4; ++t) {
                int idx = base + t;
                if (idx < 15) pu[idx] = vals[t]; else pv[idx - 15] = vals[t];
            }
        }
        { f2u v = *(const f2u*)(g2 + 28); pv[13] = v.x; pv[14] = v.y; }
        { f4u v = *(const f4u*)(gR); Rr[0] = v.x; Rr[1] = v.y; Rr[2] = v.z; Rr[3] = v.w; }
        { f4u v = *(const f4u*)(gR + 4); Rr[4] = v.x; Rr[5] = v.y; Rr[6] = v.z; Rr[7] = v.w; }
        Rr[8] = gR[8];
        { f2u v = *(const f2u*)(gC); Cc[0] = v.x; Cc[1] = v.y; }
        Cc[2] = gC[2];

        // ---- bone symmetry (f64) ----
        const int lb0[6] = {1, 5, 6, 14, 11, 12}, lb1[6] = {5, 6, 7, 11, 12, 13};
        const int rb0[6] = {1, 2, 3, 14, 8, 9},   rb1[6] = {2, 3, 4, 8, 9, 10};
        #pragma unroll
        for (int k = 0; k < 6; ++k) {
            double ll = 0.0, lr = 0.0;
            #pragma unroll
            for (int c = 0; c < 3; ++c) {
                double dl = (double)X[c * 15 + lb0[k]] - (double)X[c * 15 + lb1[k]];
                double dr = (double)X[c * 15 + rb0[k]] - (double)X[c * 15 + rb1[k]];
                ll += dl * dl;
                lr += dr * dr;
            }
            double d = ll - lr;
            sym_d += d * d;
        }

        // ---- projection (f64): P = R^T (X - C), u = 512 x/z + 512, v = 512 y/z + 256 ----
        const double R00 = Rr[0], R01 = Rr[1], R02 = Rr[2];
        const double R10 = Rr[3], R11 = Rr[4], R12 = Rr[5];
        const double R20 = Rr[6], R21 = Rr[7], R22 = Rr[8];
        const double C0 = Cc[0], C1 = Cc[1], C2 = Cc[2];
        #pragma unroll
        for (int j = 0; j < 15; ++j) {
            double q0 = (double)X[j]      - C0;
            double q1 = (double)X[15 + j] - C1;
            double q2 = (double)X[30 + j] - C2;
            double P0 = R00 * q0 + R10 * q1 + R20 * q2;
            double P1 = R01 * q0 + R11 * q1 + R21 * q2;
            double P2 = R02 * q0 + R12 * q1 + R22 * q2;
            double rz = 1.0 / P2;
            double du = 512.0 * P0 * rz + 512.0 - (double)pu[j];
            double dv = 512.0 * P1 * rz + 256.0 - (double)pv[j];
            proj_d += du * du + dv * dv;
        }
    }

    // wave shfl reduce -> LDS across 4 waves -> per-block value
    #pragma unroll
    for (int off = 32; off > 0; off >>= 1) {
        sym_d  += __shfl_down(sym_d,  off, 64);
        proj_d += __shfl_down(proj_d, off, 64);
    }
    __shared__ double s_sym[4], s_proj[4];
    const int lane = threadIdx.x & 63;
    const int wid  = threadIdx.x >> 6;
    if (lane == 0) { s_sym[wid] = sym_d; s_proj[wid] = proj_d; }
    __syncthreads();
    if (threadIdx.x == 0) {
        double sd = s_sym[0] + s_sym[1] + s_sym[2] + s_sym[3];
        double pd = s_proj[0] + s_proj[1] + s_proj[2] + s_proj[3];
        // pre-scaled: acc ends up holding the final means directly
        unsafeAtomicAdd(&acc[0], sd * inv_n_sym);
        unsafeAtomicAdd(&acc[1], pd * inv_n_proj);
        __threadfence();                       // my adds visible device-wide
        unsigned old = atomicAdd(cnt, 1u);     // device-scope ticket
        if (old == (unsigned)nblk - 1) {
            __threadfence();                   // others' adds ordered before their tickets
            double a0 = __hip_atomic_load(&acc[0], __ATOMIC_RELAXED, __HIP_MEMORY_SCOPE_AGENT);
            double a1 = __hip_atomic_load(&acc[1], __ATOMIC_RELAXED, __HIP_MEMORY_SCOPE_AGENT);
            out[0] = (float)a0;
            out[1] = (float)a1;
        }
    }
}

extern "C" void kernel_launch(void* const* d_in, const int* in_sizes, int n_in,
                              void* d_out, int out_size, void* d_ws, size_t ws_size,
                              hipStream_t stream) {
    const float* pose3d = (const float*)d_in[0];
    const float* pose2d = (const float*)d_in[1];
    const float* Rd     = (const float*)d_in[2];
    const float* Cd     = (const float*)d_in[3];

    const int B    = in_sizes[3] / 3;          // C_drone is (B,3,1)
    const int nblk = (B + 255) / 256;          // 1024 @ B=262144

    double*   acc = (double*)d_ws;                       // acc[0..1]
    unsigned* cnt = (unsigned*)((char*)d_ws + 16);       // ticket

    // acc + ticket must be zero at kernel entry on EVERY call (d_ws is
    // poisoned once, never re-poisoned between timed replays).
    hipMemsetAsync(d_ws, 0, 24, stream);

    pose_calib_main<<<nblk, 256, 0, stream>>>(
        pose3d, pose2d, Rd, Cd, acc, cnt, (float*)d_out,
        B, nblk, 1.0 / ((double)B * 6.0), 1.0 / ((double)B * 30.0));
}

// Round 7
// 56.769 us; speedup vs baseline: 1.5211x; 1.1274x over previous
//
#include <hip/hip_runtime.h>

// pose3d_calibration: B=262144 poses, J=15.
// out[0] = mean_{B,6} (|bone_l|^2 - |bone_r|^2)^2
// out[1] = mean_{B,2,15} (project(R^T (X - C)) - pose2d)^2
//
// R7: R4 body verbatim + FENCE-FREE fused epilogue.
// R5/R6 post-mortem: per-block device-scope fences (__threadfence / release
// atomics -> buffer_wbl2 L2-writeback commands) cost ~50-100us across 1024
// blocks on MI355X. Here: relaxed f64 atomic adds (coherent-point RMW needs
// no fence for visibility), ticket ordered AFTER the adds by consuming their
// return values (asm forces s_waitcnt vmcnt before the ticket issues), last
// block reads acc via +0.0 RMW (coherence-ordered). Zero wbl2 in the kernel.

typedef float f4u __attribute__((ext_vector_type(4), aligned(4)));
typedef float f2u __attribute__((ext_vector_type(2), aligned(4)));

__global__ __launch_bounds__(256, 1) void pose_calib_main(
    const float* __restrict__ pose3d,   // (B,3,15)
    const float* __restrict__ pose2d,   // (B,2,15)
    const float* __restrict__ Rd,       // (B,3,3)
    const float* __restrict__ Cd,       // (B,3,1)
    double* __restrict__ acc,           // d_ws: acc[0..1] (pre-zeroed per call)
    unsigned* __restrict__ cnt,         // d_ws: ticket (pre-zeroed per call)
    float* __restrict__ out,
    int B, int nblk, double inv_n_sym, double inv_n_proj)
{
    const int p = blockIdx.x * 256 + threadIdx.x;
    double sym_d = 0.0, proj_d = 0.0;

    if (p < B) {
        const float* g3 = pose3d + (size_t)p * 45;
        const float* g2 = pose2d + (size_t)p * 30;
        const float* gR = Rd + (size_t)p * 9;
        const float* gC = Cd + (size_t)p * 3;

        // ---- issue all loads first (wide, 4B-aligned) ----
        float X[45], pu[15], pv[15], Rr[9], Cc[3];
        #pragma unroll
        for (int k = 0; k < 11; ++k) {
            f4u v = *(const f4u*)(g3 + 4 * k);
            X[4 * k] = v.x; X[4 * k + 1] = v.y; X[4 * k + 2] = v.z; X[4 * k + 3] = v.w;
        }
        X[44] = g3[44];
        #pragma unroll
        for (int k = 0; k < 7; ++k) {
            f4u v = *(const f4u*)(g2 + 4 * k);
            int base = 4 * k;
            float vals[4] = {v.x, v.y, v.z, v.w};
            #pragma unroll
            for (int t = 0; t < 4; ++t) {
                int idx = base + t;
                if (idx < 15) pu[idx] = vals[t]; else pv[idx - 15] = vals[t];
            }
        }
        { f2u v = *(const f2u*)(g2 + 28); pv[13] = v.x; pv[14] = v.y; }
        { f4u v = *(const f4u*)(gR); Rr[0] = v.x; Rr[1] = v.y; Rr[2] = v.z; Rr[3] = v.w; }
        { f4u v = *(const f4u*)(gR + 4); Rr[4] = v.x; Rr[5] = v.y; Rr[6] = v.z; Rr[7] = v.w; }
        Rr[8] = gR[8];
        { f2u v = *(const f2u*)(gC); Cc[0] = v.x; Cc[1] = v.y; }
        Cc[2] = gC[2];

        // ---- bone symmetry (f64) ----
        const int lb0[6] = {1, 5, 6, 14, 11, 12}, lb1[6] = {5, 6, 7, 11, 12, 13};
        const int rb0[6] = {1, 2, 3, 14, 8, 9},   rb1[6] = {2, 3, 4, 8, 9, 10};
        #pragma unroll
        for (int k = 0; k < 6; ++k) {
            double ll = 0.0, lr = 0.0;
            #pragma unroll
            for (int c = 0; c < 3; ++c) {
                double dl = (double)X[c * 15 + lb0[k]] - (double)X[c * 15 + lb1[k]];
                double dr = (double)X[c * 15 + rb0[k]] - (double)X[c * 15 + rb1[k]];
                ll += dl * dl;
                lr += dr * dr;
            }
            double d = ll - lr;
            sym_d += d * d;
        }

        // ---- projection (f64): P = R^T (X - C), u = 512 x/z + 512, v = 512 y/z + 256 ----
        const double R00 = Rr[0], R01 = Rr[1], R02 = Rr[2];
        const double R10 = Rr[3], R11 = Rr[4], R12 = Rr[5];
        const double R20 = Rr[6], R21 = Rr[7], R22 = Rr[8];
        const double C0 = Cc[0], C1 = Cc[1], C2 = Cc[2];
        #pragma unroll
        for (int j = 0; j < 15; ++j) {
            double q0 = (double)X[j]      - C0;
            double q1 = (double)X[15 + j] - C1;
            double q2 = (double)X[30 + j] - C2;
            double P0 = R00 * q0 + R10 * q1 + R20 * q2;
            double P1 = R01 * q0 + R11 * q1 + R21 * q2;
            double P2 = R02 * q0 + R12 * q1 + R22 * q2;
            double rz = 1.0 / P2;
            double du = 512.0 * P0 * rz + 512.0 - (double)pu[j];
            double dv = 512.0 * P1 * rz + 256.0 - (double)pv[j];
            proj_d += du * du + dv * dv;
        }
    }

    // wave shfl reduce -> LDS across 4 waves -> per-block value
    #pragma unroll
    for (int off = 32; off > 0; off >>= 1) {
        sym_d  += __shfl_down(sym_d,  off, 64);
        proj_d += __shfl_down(proj_d, off, 64);
    }
    __shared__ double s_sym[4], s_proj[4];
    const int lane = threadIdx.x & 63;
    const int wid  = threadIdx.x >> 6;
    if (lane == 0) { s_sym[wid] = sym_d; s_proj[wid] = proj_d; }
    __syncthreads();
    if (threadIdx.x == 0) {
        double sd = s_sym[0] + s_sym[1] + s_sym[2] + s_sym[3];
        double pd = s_proj[0] + s_proj[1] + s_proj[2] + s_proj[3];
        // relaxed coherent-point RMWs; acc accumulates the final means
        double o0 = unsafeAtomicAdd(&acc[0], sd * inv_n_sym);
        double o1 = unsafeAtomicAdd(&acc[1], pd * inv_n_proj);
        // consume returned values: forces s_waitcnt vmcnt before the ticket,
        // so the ticket add issues only after my acc-adds COMPLETED at the
        // coherent point. No fence (no buffer_wbl2) anywhere.
        asm volatile("" :: "v"(o0), "v"(o1) : "memory");
        unsigned old = atomicAdd(cnt, 1u);     // relaxed device-scope ticket
        if (old == (unsigned)nblk - 1u) {
            // every block ticketed after its adds completed -> all adds are in
            // acc's coherence order before these RMW-reads.
            double a0 = unsafeAtomicAdd(&acc[0], 0.0);
            double a1 = unsafeAtomicAdd(&acc[1], 0.0);
            out[0] = (float)a0;
            out[1] = (float)a1;
        }
    }
}

extern "C" void kernel_launch(void* const* d_in, const int* in_sizes, int n_in,
                              void* d_out, int out_size, void* d_ws, size_t ws_size,
                              hipStream_t stream) {
    const float* pose3d = (const float*)d_in[0];
    const float* pose2d = (const float*)d_in[1];
    const float* Rd     = (const float*)d_in[2];
    const float* Cd     = (const float*)d_in[3];

    const int B    = in_sizes[3] / 3;          // C_drone is (B,3,1)
    const int nblk = (B + 255) / 256;          // 1024 @ B=262144

    double*   acc = (double*)d_ws;                       // acc[0..1]
    unsigned* cnt = (unsigned*)((char*)d_ws + 16);       // ticket

    // acc + ticket must be zero at kernel entry on EVERY call (d_ws is
    // poisoned once, never re-poisoned between timed replays).
    hipMemsetAsync(d_ws, 0, 24, stream);

    pose_calib_main<<<nblk, 256, 0, stream>>>(
        pose3d, pose2d, Rd, Cd, acc, cnt, (float*)d_out,
        B, nblk, 1.0 / ((double)B * 6.0), 1.0 / ((double)B * 30.0));
}

// Round 8
// 34.112 us; speedup vs baseline: 2.5313x; 1.6642x over previous
//
#include <hip/hip_runtime.h>

// pose3d_calibration: B=262144 poses, J=15.
// out[0] = mean_{B,6} (|bone_l|^2 - |bone_r|^2)^2
// out[1] = mean_{B,2,15} (project(R^T (X - C)) - pose2d)^2
//
// R8: two-kernel R4 structure (22.45us measured; no fences, no same-line
// atomics -- R5/R6/R7 showed per-block device-scope fences cost ~25us and
// 3072 same-line RMWs cost ~30us). Single change vs R4: TWO poses per
// thread, both poses' loads issued before either compute -> 2x memory-level
// parallelism per wave, half the per-pose loop overhead.

typedef float f4u __attribute__((ext_vector_type(4), aligned(4)));
typedef float f2u __attribute__((ext_vector_type(2), aligned(4)));

__device__ __forceinline__ void load_pose(
    const float* __restrict__ pose3d, const float* __restrict__ pose2d,
    const float* __restrict__ Rd, const float* __restrict__ Cd, int p,
    float (&X)[45], float (&pu)[15], float (&pv)[15], float (&Rr)[9], float (&Cc)[3])
{
    const float* g3 = pose3d + (size_t)p * 45;
    const float* g2 = pose2d + (size_t)p * 30;
    const float* gR = Rd + (size_t)p * 9;
    const float* gC = Cd + (size_t)p * 3;

    #pragma unroll
    for (int k = 0; k < 11; ++k) {
        f4u v = *(const f4u*)(g3 + 4 * k);
        X[4 * k] = v.x; X[4 * k + 1] = v.y; X[4 * k + 2] = v.z; X[4 * k + 3] = v.w;
    }
    X[44] = g3[44];
    #pragma unroll
    for (int k = 0; k < 7; ++k) {
        f4u v = *(const f4u*)(g2 + 4 * k);
        int base = 4 * k;
        float vals[4] = {v.x, v.y, v.z, v.w};
        #pragma unroll
        for (int t = 0; t < 4; ++t) {
            int idx = base + t;
            if (idx < 15) pu[idx] = vals[t]; else pv[idx - 15] = vals[t];
        }
    }
    { f2u v = *(const f2u*)(g2 + 28); pv[13] = v.x; pv[14] = v.y; }
    { f4u v = *(const f4u*)(gR); Rr[0] = v.x; Rr[1] = v.y; Rr[2] = v.z; Rr[3] = v.w; }
    { f4u v = *(const f4u*)(gR + 4); Rr[4] = v.x; Rr[5] = v.y; Rr[6] = v.z; Rr[7] = v.w; }
    Rr[8] = gR[8];
    { f2u v = *(const f2u*)(gC); Cc[0] = v.x; Cc[1] = v.y; }
    Cc[2] = gC[2];
}

__device__ __forceinline__ void compute_pose(
    const float (&X)[45], const float (&pu)[15], const float (&pv)[15],
    const float (&Rr)[9], const float (&Cc)[3],
    double& sym_d, double& proj_d)
{
    // ---- bone symmetry (f64) ----
    const int lb0[6] = {1, 5, 6, 14, 11, 12}, lb1[6] = {5, 6, 7, 11, 12, 13};
    const int rb0[6] = {1, 2, 3, 14, 8, 9},   rb1[6] = {2, 3, 4, 8, 9, 10};
    #pragma unroll
    for (int k = 0; k < 6; ++k) {
        double ll = 0.0, lr = 0.0;
        #pragma unroll
        for (int c = 0; c < 3; ++c) {
            double dl = (double)X[c * 15 + lb0[k]] - (double)X[c * 15 + lb1[k]];
            double dr = (double)X[c * 15 + rb0[k]] - (double)X[c * 15 + rb1[k]];
            ll += dl * dl;
            lr += dr * dr;
        }
        double d = ll - lr;
        sym_d += d * d;
    }

    // ---- projection (f64): P = R^T (X - C), u = 512 x/z + 512, v = 512 y/z + 256 ----
    const double R00 = Rr[0], R01 = Rr[1], R02 = Rr[2];
    const double R10 = Rr[3], R11 = Rr[4], R12 = Rr[5];
    const double R20 = Rr[6], R21 = Rr[7], R22 = Rr[8];
    const double C0 = Cc[0], C1 = Cc[1], C2 = Cc[2];
    #pragma unroll
    for (int j = 0; j < 15; ++j) {
        double q0 = (double)X[j]      - C0;
        double q1 = (double)X[15 + j] - C1;
        double q2 = (double)X[30 + j] - C2;
        double P0 = R00 * q0 + R10 * q1 + R20 * q2;
        double P1 = R01 * q0 + R11 * q1 + R21 * q2;
        double P2 = R02 * q0 + R12 * q1 + R22 * q2;
        double rz = 1.0 / P2;
        double du = 512.0 * P0 * rz + 512.0 - (double)pu[j];
        double dv = 512.0 * P1 * rz + 256.0 - (double)pv[j];
        proj_d += du * du + dv * dv;
    }
}

__global__ __launch_bounds__(256) void pose_calib_main(
    const float* __restrict__ pose3d,   // (B,3,15)
    const float* __restrict__ pose2d,   // (B,2,15)
    const float* __restrict__ Rd,       // (B,3,3)
    const float* __restrict__ Cd,       // (B,3,1)
    double* __restrict__ partial,       // (gridDim.x, 2)
    int B)
{
    const int t = blockIdx.x * 256 + threadIdx.x;
    const int p0 = t * 2;
    const int p1 = t * 2 + 1;
    double sym_d = 0.0, proj_d = 0.0;

    float XA[45], puA[15], pvA[15], RrA[9], CcA[3];
    float XB[45], puB[15], pvB[15], RrB[9], CcB[3];

    const bool haveA = (p0 < B);
    const bool haveB = (p1 < B);

    // issue BOTH poses' loads before any compute (2x MLP per wave)
    if (haveA) load_pose(pose3d, pose2d, Rd, Cd, p0, XA, puA, pvA, RrA, CcA);
    if (haveB) load_pose(pose3d, pose2d, Rd, Cd, p1, XB, puB, pvB, RrB, CcB);

    if (haveA) compute_pose(XA, puA, pvA, RrA, CcA, sym_d, proj_d);
    if (haveB) compute_pose(XB, puB, pvB, RrB, CcB, sym_d, proj_d);

    // wave shfl reduce -> LDS across 4 waves -> per-block partial
    #pragma unroll
    for (int off = 32; off > 0; off >>= 1) {
        sym_d  += __shfl_down(sym_d,  off, 64);
        proj_d += __shfl_down(proj_d, off, 64);
    }
    __shared__ double s_sym[4], s_proj[4];
    const int lane = threadIdx.x & 63;
    const int wid  = threadIdx.x >> 6;
    if (lane == 0) { s_sym[wid] = sym_d; s_proj[wid] = proj_d; }
    __syncthreads();
    if (threadIdx.x == 0) {
        partial[2 * (size_t)blockIdx.x]     = s_sym[0] + s_sym[1] + s_sym[2] + s_sym[3];
        partial[2 * (size_t)blockIdx.x + 1] = s_proj[0] + s_proj[1] + s_proj[2] + s_proj[3];
    }
}

__global__ __launch_bounds__(256) void pose_calib_finish(
    const double* __restrict__ partial, int nblk,
    float* __restrict__ out, double inv_n_sym, double inv_n_proj)
{
    const double2* p2 = (const double2*)partial;
    double ss = 0.0, pp = 0.0;
    for (int i = threadIdx.x; i < nblk; i += 256) {
        double2 v = p2[i];
        ss += v.x;
        pp += v.y;
    }
    #pragma unroll
    for (int off = 32; off > 0; off >>= 1) {
        ss += __shfl_down(ss, off, 64);
        pp += __shfl_down(pp, off, 64);
    }
    __shared__ double s_s[4], s_p[4];
    const int lane = threadIdx.x & 63;
    const int wid  = threadIdx.x >> 6;
    if (lane == 0) { s_s[wid] = ss; s_p[wid] = pp; }
    __syncthreads();
    if (threadIdx.x == 0) {
        double S = s_s[0] + s_s[1] + s_s[2] + s_s[3];
        double P = s_p[0] + s_p[1] + s_p[2] + s_p[3];
        out[0] = (float)(S * inv_n_sym);
        out[1] = (float)(P * inv_n_proj);
    }
}

extern "C" void kernel_launch(void* const* d_in, const int* in_sizes, int n_in,
                              void* d_out, int out_size, void* d_ws, size_t ws_size,
                              hipStream_t stream) {
    const float* pose3d = (const float*)d_in[0];
    const float* pose2d = (const float*)d_in[1];
    const float* Rd     = (const float*)d_in[2];
    const float* Cd     = (const float*)d_in[3];

    const int B = in_sizes[3] / 3;                 // C_drone is (B,3,1)
    const int nblk = (B + 511) / 512;              // 512 poses per block (2/thread)

    double* partial = (double*)d_ws;               // nblk*2 doubles (8 KB)

    pose_calib_main<<<nblk, 256, 0, stream>>>(pose3d, pose2d, Rd, Cd, partial, B);
    pose_calib_finish<<<1, 256, 0, stream>>>(
        partial, nblk, (float*)d_out,
        1.0 / ((double)B * 6.0), 1.0 / ((double)B * 30.0));
}

// Round 9
// 30.577 us; speedup vs baseline: 2.8240x; 1.1156x over previous
//
#include <hip/hip_runtime.h>

// pose3d_calibration: B=262144 poses, J=15.
// out[0] = mean_{B,6} (|bone_l|^2 - |bone_r|^2)^2
// out[1] = mean_{B,2,15} (project(R^T (X - C)) - pose2d)^2
//
// R9: per-wave double-buffered coalesced staging.
//  - 1-wave (64-thread) blocks; each wave owns lds[2][22272 B] (one 64-pose
//    slab per buffer). 44.5 KB/block -> 3 blocks/CU.
//  - Slab staged by 24 global_load_lds width-16 (1024 B coalesced each,
//    8 cache lines vs 64 for the per-thread pattern -> ~20x fewer L1
//    transactions than R4).
//  - Pipelined: issue next slab's 24 loads into buf^1, counted
//    s_waitcnt vmcnt(24) (NOT 0 -- next slab stays in flight), compute
//    current from LDS. No barriers in a 1-wave block, so the compiler has
//    nothing to drain at. lgkmcnt(0) before re-staging a buffer (R3-proven).
//  - Compute body is R4's f64 math verbatim (absmax 0.0 measured).

typedef const __attribute__((address_space(1))) void* gas1_t;
typedef __attribute__((address_space(3))) void* las3_t;

__device__ __forceinline__ void gl16(const float* g, float* l) {
    __builtin_amdgcn_global_load_lds((gas1_t)g, (las3_t)l, 16, 0, 0);
}

#define NBLK 1024   // main grid size (1-wave blocks); also finish's input count

__device__ __forceinline__ void compute_pose_f64(
    const float* __restrict__ X, const float* __restrict__ pu,
    const float* __restrict__ pv, const float* __restrict__ Rr,
    const float* __restrict__ Cc, double& sym_d, double& proj_d)
{
    const int lb0[6] = {1, 5, 6, 14, 11, 12}, lb1[6] = {5, 6, 7, 11, 12, 13};
    const int rb0[6] = {1, 2, 3, 14, 8, 9},   rb1[6] = {2, 3, 4, 8, 9, 10};
    #pragma unroll
    for (int k = 0; k < 6; ++k) {
        double ll = 0.0, lr = 0.0;
        #pragma unroll
        for (int c = 0; c < 3; ++c) {
            double dl = (double)X[c * 15 + lb0[k]] - (double)X[c * 15 + lb1[k]];
            double dr = (double)X[c * 15 + rb0[k]] - (double)X[c * 15 + rb1[k]];
            ll += dl * dl;
            lr += dr * dr;
        }
        double d = ll - lr;
        sym_d += d * d;
    }
    const double R00 = Rr[0], R01 = Rr[1], R02 = Rr[2];
    const double R10 = Rr[3], R11 = Rr[4], R12 = Rr[5];
    const double R20 = Rr[6], R21 = Rr[7], R22 = Rr[8];
    const double C0 = Cc[0], C1 = Cc[1], C2 = Cc[2];
    #pragma unroll
    for (int j = 0; j < 15; ++j) {
        double q0 = (double)X[j]      - C0;
        double q1 = (double)X[15 + j] - C1;
        double q2 = (double)X[30 + j] - C2;
        double P0 = R00 * q0 + R10 * q1 + R20 * q2;
        double P1 = R01 * q0 + R11 * q1 + R21 * q2;
        double P2 = R02 * q0 + R12 * q1 + R22 * q2;
        double rz = 1.0 / P2;
        double du = 512.0 * P0 * rz + 512.0 - (double)pu[j];
        double dv = 512.0 * P1 * rz + 256.0 - (double)pv[j];
        proj_d += du * du + dv * dv;
    }
}

__global__ __launch_bounds__(64) void pose_calib_main(
    const float* __restrict__ pose3d,   // (B,3,15)
    const float* __restrict__ pose2d,   // (B,2,15)
    const float* __restrict__ Rd,       // (B,3,3)
    const float* __restrict__ Cd,       // (B,3,1)
    double* __restrict__ partial,       // (NBLK,2)
    int B)
{
    // per-buffer float layout: X[2880] | p2[1920] | R[576] | C[192]  = 5568 f
    __shared__ float lds[2][5568];

    const int lane  = threadIdx.x;      // 0..63
    const int nslab = B >> 6;           // full 64-pose slabs
    double sym_d = 0.0, proj_d = 0.0;

    // ---- coalesced stage of slab s into buffer b: exactly 24 gl16 ----
    auto stage = [&](int s, int b) {
        const float* g3 = pose3d + (size_t)s * 2880;
        const float* g2 = pose2d + (size_t)s * 1920;
        const float* gR = Rd     + (size_t)s * 576;
        const float* gC = Cd     + (size_t)s * 192;
        float* sX = &lds[b][0];
        float* sP = &lds[b][2880];
        float* sR = &lds[b][4800];
        float* sC = &lds[b][5376];
        #pragma unroll
        for (int k = 0; k < 11; ++k) gl16(g3 + k * 256 + lane * 4, sX + k * 256);
        gl16(g3 + 2624 + lane * 4, sX + 2624);          // tail overlap [2624,2880)
        #pragma unroll
        for (int k = 0; k < 7; ++k) gl16(g2 + k * 256 + lane * 4, sP + k * 256);
        gl16(g2 + 1664 + lane * 4, sP + 1664);          // tail overlap [1664,1920)
        gl16(gR + lane * 4, sR);
        gl16(gR + 256 + lane * 4, sR + 256);
        gl16(gR + 320 + lane * 4, sR + 320);            // tail overlap [320,576)
        if (lane < 48) gl16(gC + lane * 4, sC);         // 192 floats, 48 lanes
    };

    int  slab = blockIdx.x;
    int  cur  = 0;
    bool have = (slab < nslab);
    if (have) stage(slab, 0);

    while (have) {
        const int  nxt      = slab + NBLK;              // gridDim.x == NBLK
        const bool have_nxt = (nxt < nslab);

        // previous iteration's ds_reads of buf cur^1 must be fully retired
        // before the DMA below overwrites it (cheap: they were consumed).
        asm volatile("s_waitcnt lgkmcnt(0)" ::: "memory");
        if (have_nxt) stage(nxt, cur ^ 1);

        // wait for CURRENT buffer's 24 loads only; next slab stays in flight
        if (have_nxt) asm volatile("s_waitcnt vmcnt(24)" ::: "memory");
        else          asm volatile("s_waitcnt vmcnt(0)"  ::: "memory");
        __builtin_amdgcn_sched_barrier(0);

        {
            const float* sX = &lds[cur][0];
            const float* sP = &lds[cur][2880];
            const float* sR = &lds[cur][4800];
            const float* sC = &lds[cur][5376];
            float X[45], pu[15], pv[15], Rr[9], Cc[3];
            #pragma unroll
            for (int i = 0; i < 45; ++i) X[i] = sX[lane * 45 + i];   // 2 lanes/bank: free
            #pragma unroll
            for (int j = 0; j < 15; ++j) { pu[j] = sP[lane * 30 + j]; pv[j] = sP[lane * 30 + 15 + j]; }
            #pragma unroll
            for (int k = 0; k < 9; ++k) Rr[k] = sR[lane * 9 + k];
            #pragma unroll
            for (int c = 0; c < 3; ++c) Cc[c] = sC[lane * 3 + c];
            compute_pose_f64(X, pu, pv, Rr, Cc, sym_d, proj_d);
        }

        slab = nxt; have = have_nxt; cur ^= 1;
    }

    // ---- ragged tail (B % 64 poses): one designated block, direct loads ----
    if ((B & 63) && blockIdx.x == (unsigned)(nslab % NBLK)) {
        const int p = nslab * 64 + lane;
        if (p < B) {
            const float* g3 = pose3d + (size_t)p * 45;
            const float* g2 = pose2d + (size_t)p * 30;
            const float* gR = Rd + (size_t)p * 9;
            const float* gC = Cd + (size_t)p * 3;
            float X[45], pu[15], pv[15], Rr[9], Cc[3];
            #pragma unroll
            for (int i = 0; i < 45; ++i) X[i] = g3[i];
            #pragma unroll
            for (int j = 0; j < 15; ++j) { pu[j] = g2[j]; pv[j] = g2[15 + j]; }
            #pragma unroll
            for (int k = 0; k < 9; ++k) Rr[k] = gR[k];
            #pragma unroll
            for (int c = 0; c < 3; ++c) Cc[c] = gC[c];
            compute_pose_f64(X, pu, pv, Rr, Cc, sym_d, proj_d);
        }
    }

    // ---- wave-wide f64 reduction (single wave per block) ----
    #pragma unroll
    for (int off = 32; off > 0; off >>= 1) {
        sym_d  += __shfl_down(sym_d,  off, 64);
        proj_d += __shfl_down(proj_d, off, 64);
    }
    if (lane == 0) {
        partial[2 * (size_t)blockIdx.x]     = sym_d;
        partial[2 * (size_t)blockIdx.x + 1] = proj_d;
    }
}

__global__ __launch_bounds__(256) void pose_calib_finish(
    const double* __restrict__ partial, int nblk,
    float* __restrict__ out, double inv_n_sym, double inv_n_proj)
{
    const double2* p2 = (const double2*)partial;
    double ss = 0.0, pp = 0.0;
    for (int i = threadIdx.x; i < nblk; i += 256) {
        double2 v = p2[i];
        ss += v.x;
        pp += v.y;
    }
    #pragma unroll
    for (int off = 32; off > 0; off >>= 1) {
        ss += __shfl_down(ss, off, 64);
        pp += __shfl_down(pp, off, 64);
    }
    __shared__ double s_s[4], s_p[4];
    const int lane = threadIdx.x & 63;
    const int wid  = threadIdx.x >> 6;
    if (lane == 0) { s_s[wid] = ss; s_p[wid] = pp; }
    __syncthreads();
    if (threadIdx.x == 0) {
        double S = s_s[0] + s_s[1] + s_s[2] + s_s[3];
        double P = s_p[0] + s_p[1] + s_p[2] + s_p[3];
        out[0] = (float)(S * inv_n_sym);
        out[1] = (float)(P * inv_n_proj);
    }
}

extern "C" void kernel_launch(void* const* d_in, const int* in_sizes, int n_in,
                              void* d_out, int out_size, void* d_ws, size_t ws_size,
                              hipStream_t stream) {
    const float* pose3d = (const float*)d_in[0];
    const float* pose2d = (const float*)d_in[1];
    const float* Rd     = (const float*)d_in[2];
    const float* Cd     = (const float*)d_in[3];

    const int B = in_sizes[3] / 3;     // C_drone is (B,3,1)

    double* partial = (double*)d_ws;   // NBLK*2 doubles (16 KB)

    pose_calib_main<<<NBLK, 64, 0, stream>>>(pose3d, pose2d, Rd, Cd, partial, B);
    pose_calib_finish<<<1, 256, 0, stream>>>(
        partial, NBLK, (float*)d_out,
        1.0 / ((double)B * 6.0), 1.0 / ((double)B * 30.0));
}

// Round 10
// 28.696 us; speedup vs baseline: 3.0092x; 1.0656x over previous
//
#include <hip/hip_runtime.h>

// pose3d_calibration: B=262144 poses, J=15.
// out[0] = mean_{B,6} (|bone_l|^2 - |bone_r|^2)^2
// out[1] = mean_{B,2,15} (project(R^T (X - C)) - pose2d)^2
//
// R10: R4 structure verbatim (2 kernels, per-thread float4 loads, 22.45us
// measured) with ONE change: mixed-precision compute.
//   f64 ONLY where cancellation demands it: q = X - C and z = R[.,2] . q
//   (z ~ 1e-4 from cancelling O(5) terms). Everything else f32: P0/P1 dots
//   (no cancellation, rel err ~5e-6), 1/z via f32 rcp of the accurately-
//   computed z (representation error 1e-7), u/v/du/dv/squares, bones.
//   Output error budget ~1e2-1e3 absolute << 1.57e6 threshold.
// Removes all 15 f64 divides (~150 f64 instrs) and ~2/3 of f64 FMA work:
// shorter dependent tail per pose + lower VGPR -> better latency hiding at
// the same 16 waves/CU.

typedef float f4u __attribute__((ext_vector_type(4), aligned(4)));
typedef float f2u __attribute__((ext_vector_type(2), aligned(4)));

__global__ __launch_bounds__(256) void pose_calib_main(
    const float* __restrict__ pose3d,   // (B,3,15)
    const float* __restrict__ pose2d,   // (B,2,15)
    const float* __restrict__ Rd,       // (B,3,3)
    const float* __restrict__ Cd,       // (B,3,1)
    double* __restrict__ partial,       // (gridDim.x, 2)
    int B)
{
    const int p = blockIdx.x * 256 + threadIdx.x;
    double sym_d = 0.0, proj_d = 0.0;

    if (p < B) {
        const float* g3 = pose3d + (size_t)p * 45;
        const float* g2 = pose2d + (size_t)p * 30;
        const float* gR = Rd + (size_t)p * 9;
        const float* gC = Cd + (size_t)p * 3;

        // ---- issue all loads first (wide, 4B-aligned) — R4 verbatim ----
        float X[45], pu[15], pv[15], Rr[9], Cc[3];
        #pragma unroll
        for (int k = 0; k < 11; ++k) {
            f4u v = *(const f4u*)(g3 + 4 * k);
            X[4 * k] = v.x; X[4 * k + 1] = v.y; X[4 * k + 2] = v.z; X[4 * k + 3] = v.w;
        }
        X[44] = g3[44];
        #pragma unroll
        for (int k = 0; k < 7; ++k) {
            f4u v = *(const f4u*)(g2 + 4 * k);
            int base = 4 * k;
            float vals[4] = {v.x, v.y, v.z, v.w};
            #pragma unroll
            for (int t = 0; t < 4; ++t) {
                int idx = base + t;
                if (idx < 15) pu[idx] = vals[t]; else pv[idx - 15] = vals[t];
            }
        }
        { f2u v = *(const f2u*)(g2 + 28); pv[13] = v.x; pv[14] = v.y; }
        { f4u v = *(const f4u*)(gR); Rr[0] = v.x; Rr[1] = v.y; Rr[2] = v.z; Rr[3] = v.w; }
        { f4u v = *(const f4u*)(gR + 4); Rr[4] = v.x; Rr[5] = v.y; Rr[6] = v.z; Rr[7] = v.w; }
        Rr[8] = gR[8];
        { f2u v = *(const f2u*)(gC); Cc[0] = v.x; Cc[1] = v.y; }
        Cc[2] = gC[2];

        // ---- bone symmetry: all f32 (abs err ~1e-5, irrelevant vs 1.57e6) ----
        float sym_f = 0.0f;
        const int lb0[6] = {1, 5, 6, 14, 11, 12}, lb1[6] = {5, 6, 7, 11, 12, 13};
        const int rb0[6] = {1, 2, 3, 14, 8, 9},   rb1[6] = {2, 3, 4, 8, 9, 10};
        #pragma unroll
        for (int k = 0; k < 6; ++k) {
            float ll = 0.f, lr = 0.f;
            #pragma unroll
            for (int c = 0; c < 3; ++c) {
                float dl = X[c * 15 + lb0[k]] - X[c * 15 + lb1[k]];
                float dr = X[c * 15 + rb0[k]] - X[c * 15 + rb1[k]];
                ll += dl * dl;
                lr += dr * dr;
            }
            float d = ll - lr;
            sym_f += d * d;
        }
        sym_d = (double)sym_f;

        // ---- projection: f64 only for q and z; rest f32 ----
        const double C0 = (double)Cc[0], C1 = (double)Cc[1], C2 = (double)Cc[2];
        const double Rz0 = (double)Rr[2], Rz1 = (double)Rr[5], Rz2 = (double)Rr[8];
        float proj_f = 0.0f;
        #pragma unroll
        for (int j = 0; j < 15; ++j) {
            double q0 = (double)X[j]      - C0;
            double q1 = (double)X[15 + j] - C1;
            double q2 = (double)X[30 + j] - C2;
            double Pz = Rz0 * q0 + Rz1 * q1 + Rz2 * q2;   // cancellation-critical
            float q0f = (float)q0, q1f = (float)q1, q2f = (float)q2;
            float P0 = Rr[0] * q0f + Rr[3] * q1f + Rr[6] * q2f;
            float P1 = Rr[1] * q0f + Rr[4] * q1f + Rr[7] * q2f;
            float rz = 512.0f / (float)Pz;                // z accurate; f32 rcp fine
            float du = P0 * rz + 512.0f - pu[j];
            float dv = P1 * rz + 256.0f - pv[j];
            proj_f += du * du + dv * dv;
        }
        proj_d = (double)proj_f;
    }

    // wave shfl reduce -> LDS across 4 waves -> per-block partial (R4 verbatim)
    #pragma unroll
    for (int off = 32; off > 0; off >>= 1) {
        sym_d  += __shfl_down(sym_d,  off, 64);
        proj_d += __shfl_down(proj_d, off, 64);
    }
    __shared__ double s_sym[4], s_proj[4];
    const int lane = threadIdx.x & 63;
    const int wid  = threadIdx.x >> 6;
    if (lane == 0) { s_sym[wid] = sym_d; s_proj[wid] = proj_d; }
    __syncthreads();
    if (threadIdx.x == 0) {
        partial[2 * (size_t)blockIdx.x]     = s_sym[0] + s_sym[1] + s_sym[2] + s_sym[3];
        partial[2 * (size_t)blockIdx.x + 1] = s_proj[0] + s_proj[1] + s_proj[2] + s_proj[3];
    }
}

__global__ __launch_bounds__(256) void pose_calib_finish(
    const double* __restrict__ partial, int nblk,
    float* __restrict__ out, double inv_n_sym, double inv_n_proj)
{
    const double2* p2 = (const double2*)partial;
    double ss = 0.0, pp = 0.0;
    for (int i = threadIdx.x; i < nblk; i += 256) {
        double2 v = p2[i];
        ss += v.x;
        pp += v.y;
    }
    #pragma unroll
    for (int off = 32; off > 0; off >>= 1) {
        ss += __shfl_down(ss, off, 64);
        pp += __shfl_down(pp, off, 64);
    }
    __shared__ double s_s[4], s_p[4];
    const int lane = threadIdx.x & 63;
    const int wid  = threadIdx.x >> 6;
    if (lane == 0) { s_s[wid] = ss; s_p[wid] = pp; }
    __syncthreads();
    if (threadIdx.x == 0) {
        double S = s_s[0] + s_s[1] + s_s[2] + s_s[3];
        double P = s_p[0] + s_p[1] + s_p[2] + s_p[3];
        out[0] = (float)(S * inv_n_sym);
        out[1] = (float)(P * inv_n_proj);
    }
}

extern "C" void kernel_launch(void* const* d_in, const int* in_sizes, int n_in,
                              void* d_out, int out_size, void* d_ws, size_t ws_size,
                              hipStream_t stream) {
    const float* pose3d = (const float*)d_in[0];
    const float* pose2d = (const float*)d_in[1];
    const float* Rd     = (const float*)d_in[2];
    const float* Cd     = (const float*)d_in[3];

    const int B = in_sizes[3] / 3;                 // C_drone is (B,3,1)
    const int nblk = (B + 255) / 256;              // 1024 @ B=262144

    double* partial = (double*)d_ws;               // nblk*2 doubles (16 KB)

    pose_calib_main<<<nblk, 256, 0, stream>>>(pose3d, pose2d, Rd, Cd, partial, B);
    pose_calib_finish<<<1, 256, 0, stream>>>(
        partial, nblk, (float*)d_out,
        1.0 / ((double)B * 6.0), 1.0 / ((double)B * 30.0));
}

// Round 11
// 23.907 us; speedup vs baseline: 3.6118x; 1.2003x over previous
//
#include <hip/hip_runtime.h>

// pose3d_calibration: B=262144 poses, J=15.
// out[0] = mean_{B,6} (|bone_l|^2 - |bone_r|^2)^2
// out[1] = mean_{B,2,15} (project(R^T (X - C)) - pose2d)^2
//
// R11: coalesced staging + high occupancy ("wave-per-part").
//  - 256-thread block owns ONE 64-pose slab (22.3 KB LDS -> 7 blocks/CU,
//    28 waves/CU; R9's occupancy trap was 1-wave blocks at 3 waves/CU).
//  - Slab staged by exactly 24 global_load_lds width-16 (1024B coalesced
//    each; ~200 L1 line-touches vs ~1600 for R4's per-thread float4 loads
//    -- the TA-transaction bottleneck that capped R4 at ~13.5us).
//  - Staging split 6 gl16 per wave; one __syncthreads (256-thread barrier
//    emits s_waitcnt vmcnt(0) before s_barrier -- m97-proven, R3-verified).
//  - Compute: wave w = part w, lane = pose. Wave-uniform branches, all
//    joint/bone indices compile-time. Waves 0..3: joints {0-3},{4-7},
//    {8-11},{12-14}; bones {0,1},{2,3},{4},{5}.
//  - Full f64 math (bit-matched np ref in R1/R3/R4).

typedef const __attribute__((address_space(1))) void* gas1_t;
typedef __attribute__((address_space(3))) void* las3_t;

__device__ __forceinline__ void gl16(const float* g, float* l) {
    __builtin_amdgcn_global_load_lds((gas1_t)g, (las3_t)l, 16, 0, 0);
}

__device__ __forceinline__ void proj_joint(
    const float* __restrict__ X, const float* __restrict__ P2, int j,
    const double (&Rr)[9], double C0, double C1, double C2, double& proj_d)
{
    double q0 = (double)X[j]      - C0;
    double q1 = (double)X[15 + j] - C1;
    double q2 = (double)X[30 + j] - C2;
    double P0 = Rr[0] * q0 + Rr[3] * q1 + Rr[6] * q2;
    double P1 = Rr[1] * q0 + Rr[4] * q1 + Rr[7] * q2;
    double Pz = Rr[2] * q0 + Rr[5] * q1 + Rr[8] * q2;
    double rz = 1.0 / Pz;
    double du = 512.0 * P0 * rz + 512.0 - (double)P2[j];
    double dv = 512.0 * P1 * rz + 256.0 - (double)P2[15 + j];
    proj_d += du * du + dv * dv;
}

__device__ __forceinline__ void bone_term(
    const float* __restrict__ X, int l0, int l1, int r0, int r1, double& sym_d)
{
    double ll = 0.0, lr = 0.0;
    #pragma unroll
    for (int c = 0; c < 3; ++c) {
        double dl = (double)X[c * 15 + l0] - (double)X[c * 15 + l1];
        double dr = (double)X[c * 15 + r0] - (double)X[c * 15 + r1];
        ll += dl * dl;
        lr += dr * dr;
    }
    double d = ll - lr;
    sym_d += d * d;
}

__global__ __launch_bounds__(256) void pose_calib_main(
    const float* __restrict__ pose3d,   // (B,3,15)
    const float* __restrict__ pose2d,   // (B,2,15)
    const float* __restrict__ Rd,       // (B,3,3)
    const float* __restrict__ Cd,       // (B,3,1)
    double* __restrict__ partial,       // (nblk,2)
    int B)
{
    __shared__ float sl[5568];          // X[2880] | p2[1920] | R[576] | C[192]
    __shared__ double s_sym[4], s_proj[4];

    const int tid  = threadIdx.x;
    const int lane = tid & 63;          // = pose-in-slab
    const int wid  = tid >> 6;          // = part
    const long long p0 = (long long)blockIdx.x * 64;
    const bool fullslab = (p0 + 64 <= (long long)B);

    double sym_d = 0.0, proj_d = 0.0;

    if (fullslab) {
        const float* g3 = pose3d + p0 * 45;
        const float* g2 = pose2d + p0 * 30;
        const float* gR = Rd + p0 * 9;
        const float* gC = Cd + p0 * 3;

        // ---- 24 coalesced gl16, 6 per wave (wave-uniform branches) ----
        if (wid == 0) {
            #pragma unroll
            for (int k = 0; k < 6; ++k) gl16(g3 + k * 256 + lane * 4, sl + k * 256);
        } else if (wid == 1) {
            #pragma unroll
            for (int k = 6; k < 11; ++k) gl16(g3 + k * 256 + lane * 4, sl + k * 256);
            gl16(g3 + 2624 + lane * 4, sl + 2624);             // X tail [2624,2880)
        } else if (wid == 2) {
            #pragma unroll
            for (int k = 0; k < 6; ++k) gl16(g2 + k * 256 + lane * 4, sl + 2880 + k * 256);
        } else {
            gl16(g2 + 1536 + lane * 4, sl + 2880 + 1536);      // p2 row 6
            gl16(g2 + 1664 + lane * 4, sl + 2880 + 1664);      // p2 tail [1664,1920)
            gl16(gR + lane * 4,        sl + 4800);             // R [0,256)
            gl16(gR + 256 + lane * 4,  sl + 5056);             // R [256,512)
            gl16(gR + 320 + lane * 4,  sl + 5120);             // R tail [320,576)
            if (lane < 48) gl16(gC + lane * 4, sl + 5376);     // C [0,192)
        }
        __syncthreads();   // 256-thread barrier: s_waitcnt vmcnt(0) + s_barrier

        const float* X  = sl + lane * 45;           // stride 45: 2/bank, free
        const float* P2 = sl + 2880 + lane * 30;    // stride 30: 4-way, 1.58x on 8 reads
        const float* Rf = sl + 4800 + lane * 9;     // stride 9: 2/bank, free
        const float* Cf = sl + 5376 + lane * 3;     // stride 3: 2/bank, free

        double Rr[9];
        #pragma unroll
        for (int k = 0; k < 9; ++k) Rr[k] = (double)Rf[k];
        const double C0 = (double)Cf[0], C1 = (double)Cf[1], C2 = (double)Cf[2];

        // bones: LEFT (1,5)(5,6)(6,7)(14,11)(11,12)(12,13)
        //        RIGHT(1,2)(2,3)(3,4)(14,8)(8,9)(9,10)
        if (wid == 0) {
            proj_joint(X, P2, 0, Rr, C0, C1, C2, proj_d);
            proj_joint(X, P2, 1, Rr, C0, C1, C2, proj_d);
            proj_joint(X, P2, 2, Rr, C0, C1, C2, proj_d);
            proj_joint(X, P2, 3, Rr, C0, C1, C2, proj_d);
            bone_term(X, 1, 5, 1, 2, sym_d);
            bone_term(X, 5, 6, 2, 3, sym_d);
        } else if (wid == 1) {
            proj_joint(X, P2, 4, Rr, C0, C1, C2, proj_d);
            proj_joint(X, P2, 5, Rr, C0, C1, C2, proj_d);
            proj_joint(X, P2, 6, Rr, C0, C1, C2, proj_d);
            proj_joint(X, P2, 7, Rr, C0, C1, C2, proj_d);
            bone_term(X, 6, 7, 3, 4, sym_d);
            bone_term(X, 14, 11, 14, 8, sym_d);
        } else if (wid == 2) {
            proj_joint(X, P2, 8, Rr, C0, C1, C2, proj_d);
            proj_joint(X, P2, 9, Rr, C0, C1, C2, proj_d);
            proj_joint(X, P2, 10, Rr, C0, C1, C2, proj_d);
            proj_joint(X, P2, 11, Rr, C0, C1, C2, proj_d);
            bone_term(X, 11, 12, 8, 9, sym_d);
        } else {
            proj_joint(X, P2, 12, Rr, C0, C1, C2, proj_d);
            proj_joint(X, P2, 13, Rr, C0, C1, C2, proj_d);
            proj_joint(X, P2, 14, Rr, C0, C1, C2, proj_d);
            bone_term(X, 12, 13, 9, 10, sym_d);
        }
    } else {
        // ---- tail slab (not hit at B=262144): guarded scalar fallback ----
        const long long p = p0 + lane;
        if (p < (long long)B) {
            const float* g3 = pose3d + p * 45;
            const float* g2 = pose2d + p * 30;
            const float* gR = Rd + p * 9;
            const float* gC = Cd + p * 3;
            float X[45], P2l[30];
            #pragma unroll
            for (int i = 0; i < 45; ++i) X[i] = g3[i];
            #pragma unroll
            for (int i = 0; i < 30; ++i) P2l[i] = g2[i];
            double Rr[9];
            #pragma unroll
            for (int k = 0; k < 9; ++k) Rr[k] = (double)gR[k];
            const double C0 = gC[0], C1 = gC[1], C2 = gC[2];
            if (wid == 0) {
                proj_joint(X, P2l, 0, Rr, C0, C1, C2, proj_d);
                proj_joint(X, P2l, 1, Rr, C0, C1, C2, proj_d);
                proj_joint(X, P2l, 2, Rr, C0, C1, C2, proj_d);
                proj_joint(X, P2l, 3, Rr, C0, C1, C2, proj_d);
                bone_term(X, 1, 5, 1, 2, sym_d);
                bone_term(X, 5, 6, 2, 3, sym_d);
            } else if (wid == 1) {
                proj_joint(X, P2l, 4, Rr, C0, C1, C2, proj_d);
                proj_joint(X, P2l, 5, Rr, C0, C1, C2, proj_d);
                proj_joint(X, P2l, 6, Rr, C0, C1, C2, proj_d);
                proj_joint(X, P2l, 7, Rr, C0, C1, C2, proj_d);
                bone_term(X, 6, 7, 3, 4, sym_d);
                bone_term(X, 14, 11, 14, 8, sym_d);
            } else if (wid == 2) {
                proj_joint(X, P2l, 8, Rr, C0, C1, C2, proj_d);
                proj_joint(X, P2l, 9, Rr, C0, C1, C2, proj_d);
                proj_joint(X, P2l, 10, Rr, C0, C1, C2, proj_d);
                proj_joint(X, P2l, 11, Rr, C0, C1, C2, proj_d);
                bone_term(X, 11, 12, 8, 9, sym_d);
            } else {
                proj_joint(X, P2l, 12, Rr, C0, C1, C2, proj_d);
                proj_joint(X, P2l, 13, Rr, C0, C1, C2, proj_d);
                proj_joint(X, P2l, 14, Rr, C0, C1, C2, proj_d);
                bone_term(X, 12, 13, 9, 10, sym_d);
            }
        }
        __syncthreads();   // keep barrier count uniform across branches
    }

    // ---- block reduction: wave shfl -> LDS across 4 waves ----
    #pragma unroll
    for (int off = 32; off > 0; off >>= 1) {
        sym_d  += __shfl_down(sym_d,  off, 64);
        proj_d += __shfl_down(proj_d, off, 64);
    }
    if (lane == 0) { s_sym[wid] = sym_d; s_proj[wid] = proj_d; }
    __syncthreads();
    if (tid == 0) {
        partial[2 * (size_t)blockIdx.x]     = s_sym[0] + s_sym[1] + s_sym[2] + s_sym[3];
        partial[2 * (size_t)blockIdx.x + 1] = s_proj[0] + s_proj[1] + s_proj[2] + s_proj[3];
    }
}

__global__ __launch_bounds__(1024) void pose_calib_finish(
    const double* __restrict__ partial, int nblk,
    float* __restrict__ out, double inv_n_sym, double inv_n_proj)
{
    const double2* p2 = (const double2*)partial;
    double ss = 0.0, pp = 0.0;
    for (int i = threadIdx.x; i < nblk; i += 1024) {
        double2 v = p2[i];
        ss += v.x;
        pp += v.y;
    }
    #pragma unroll
    for (int off = 32; off > 0; off >>= 1) {
        ss += __shfl_down(ss, off, 64);
        pp += __shfl_down(pp, off, 64);
    }
    __shared__ double s_s[16], s_p[16];
    const int lane = threadIdx.x & 63;
    const int wid  = threadIdx.x >> 6;
    if (lane == 0) { s_s[wid] = ss; s_p[wid] = pp; }
    __syncthreads();
    if (threadIdx.x == 0) {
        double S = 0.0, P = 0.0;
        #pragma unroll
        for (int k = 0; k < 16; ++k) { S += s_s[k]; P += s_p[k]; }
        out[0] = (float)(S * inv_n_sym);
        out[1] = (float)(P * inv_n_proj);
    }
}

extern "C" void kernel_launch(void* const* d_in, const int* in_sizes, int n_in,
                              void* d_out, int out_size, void* d_ws, size_t ws_size,
                              hipStream_t stream) {
    const float* pose3d = (const float*)d_in[0];
    const float* pose2d = (const float*)d_in[1];
    const float* Rd     = (const float*)d_in[2];
    const float* Cd     = (const float*)d_in[3];

    const int B    = in_sizes[3] / 3;      // C_drone is (B,3,1)
    const int nblk = (B + 63) / 64;        // 4096 @ B=262144 (64 poses/block)

    double* partial = (double*)d_ws;       // nblk*2 doubles (64 KB)

    pose_calib_main<<<nblk, 256, 0, stream>>>(pose3d, pose2d, Rd, Cd, partial, B);
    pose_calib_finish<<<1, 1024, 0, stream>>>(
        partial, nblk, (float*)d_out,
        1.0 / ((double)B * 6.0), 1.0 / ((double)B * 30.0));
}

// Round 12
// 22.365 us; speedup vs baseline: 3.8609x; 1.0689x over previous
//
#include <hip/hip_runtime.h>

// pose3d_calibration: B=262144 poses, J=15.
// out[0] = mean_{B,6} (|bone_l|^2 - |bone_r|^2)^2
// out[1] = mean_{B,2,15} (project(R^T (X - C)) - pose2d)^2
//
// R12 = R4 verbatim (best measured: 22.45us), restored as the final artifact.
// Session evidence for why this is the floor:
//  - Replays are L3-resident (R5-R7: hbm_bytes ~0.1MB) and both antipodal
//    memory structures (per-thread float4 loads here; 24x coalesced
//    global_load_lds in R11) converge to main ~13us = 91.2MB @ ~7.0 TB/s,
//    equal to the measured fill-kernel ceiling -> memory-side BW floor.
//  - Fused single-kernel epilogues are dead: per-block device-scope fences
//    cost ~25-50us (R5/R6), same-line f64 RMW serialization ~30us (R7).
//  - VALU cuts don't help (R10), MLP doesn't help (R8), occupancy-starved
//    coalescing hurts (R3/R9).
// Budget: ~8us graph/launch overhead + ~13us main (BW floor) + ~2us finish.

typedef float f4u __attribute__((ext_vector_type(4), aligned(4)));
typedef float f2u __attribute__((ext_vector_type(2), aligned(4)));

__global__ __launch_bounds__(256) void pose_calib_main(
    const float* __restrict__ pose3d,   // (B,3,15)
    const float* __restrict__ pose2d,   // (B,2,15)
    const float* __restrict__ Rd,       // (B,3,3)
    const float* __restrict__ Cd,       // (B,3,1)
    double* __restrict__ partial,       // (gridDim.x, 2)
    int B)
{
    const int p = blockIdx.x * 256 + threadIdx.x;
    double sym_d = 0.0, proj_d = 0.0;

    if (p < B) {
        const float* g3 = pose3d + (size_t)p * 45;
        const float* g2 = pose2d + (size_t)p * 30;
        const float* gR = Rd + (size_t)p * 9;
        const float* gC = Cd + (size_t)p * 3;

        // ---- issue all loads first (wide, 4B-aligned) ----
        float X[45], pu[15], pv[15], Rr[9], Cc[3];
        #pragma unroll
        for (int k = 0; k < 11; ++k) {
            f4u v = *(const f4u*)(g3 + 4 * k);
            X[4 * k] = v.x; X[4 * k + 1] = v.y; X[4 * k + 2] = v.z; X[4 * k + 3] = v.w;
        }
        X[44] = g3[44];
        #pragma unroll
        for (int k = 0; k < 7; ++k) {
            f4u v = *(const f4u*)(g2 + 4 * k);
            float* d = (k < 4) ? &pu[4 * k] : &pv[4 * k - 15];
            // avoid dynamic pointer games; just index directly:
            (void)d;
            int base = 4 * k;
            float vals[4] = {v.x, v.y, v.z, v.w};
            #pragma unroll
            for (int t = 0; t < 4; ++t) {
                int idx = base + t;
                if (idx < 15) pu[idx] = vals[t]; else pv[idx - 15] = vals[t];
            }
        }
        { f2u v = *(const f2u*)(g2 + 28); pv[13] = v.x; pv[14] = v.y; }
        { f4u v = *(const f4u*)(gR); Rr[0] = v.x; Rr[1] = v.y; Rr[2] = v.z; Rr[3] = v.w; }
        { f4u v = *(const f4u*)(gR + 4); Rr[4] = v.x; Rr[5] = v.y; Rr[6] = v.z; Rr[7] = v.w; }
        Rr[8] = gR[8];
        { f2u v = *(const f2u*)(gC); Cc[0] = v.x; Cc[1] = v.y; }
        Cc[2] = gC[2];

        // ---- bone symmetry (f64) ----
        const int lb0[6] = {1, 5, 6, 14, 11, 12}, lb1[6] = {5, 6, 7, 11, 12, 13};
        const int rb0[6] = {1, 2, 3, 14, 8, 9},   rb1[6] = {2, 3, 4, 8, 9, 10};
        #pragma unroll
        for (int k = 0; k < 6; ++k) {
            double ll = 0.0, lr = 0.0;
            #pragma unroll
            for (int c = 0; c < 3; ++c) {
                double dl = (double)X[c * 15 + lb0[k]] - (double)X[c * 15 + lb1[k]];
                double dr = (double)X[c * 15 + rb0[k]] - (double)X[c * 15 + rb1[k]];
                ll += dl * dl;
                lr += dr * dr;
            }
            double d = ll - lr;
            sym_d += d * d;
        }

        // ---- projection (f64): P = R^T (X - C), u = 512 x/z + 512, v = 512 y/z + 256 ----
        const double R00 = Rr[0], R01 = Rr[1], R02 = Rr[2];
        const double R10 = Rr[3], R11 = Rr[4], R12 = Rr[5];
        const double R20 = Rr[6], R21 = Rr[7], R22 = Rr[8];
        const double C0 = Cc[0], C1 = Cc[1], C2 = Cc[2];
        #pragma unroll
        for (int j = 0; j < 15; ++j) {
            double q0 = (double)X[j]      - C0;
            double q1 = (double)X[15 + j] - C1;
            double q2 = (double)X[30 + j] - C2;
            double P0 = R00 * q0 + R10 * q1 + R20 * q2;
            double P1 = R01 * q0 + R11 * q1 + R21 * q2;
            double P2 = R02 * q0 + R12 * q1 + R22 * q2;
            double rz = 1.0 / P2;
            double du = 512.0 * P0 * rz + 512.0 - (double)pu[j];
            double dv = 512.0 * P1 * rz + 256.0 - (double)pv[j];
            proj_d += du * du + dv * dv;
        }
    }

    // wave shfl reduce -> LDS across 4 waves -> per-block partial
    #pragma unroll
    for (int off = 32; off > 0; off >>= 1) {
        sym_d  += __shfl_down(sym_d,  off, 64);
        proj_d += __shfl_down(proj_d, off, 64);
    }
    __shared__ double s_sym[4], s_proj[4];
    const int lane = threadIdx.x & 63;
    const int wid  = threadIdx.x >> 6;
    if (lane == 0) { s_sym[wid] = sym_d; s_proj[wid] = proj_d; }
    __syncthreads();
    if (threadIdx.x == 0) {
        partial[2 * (size_t)blockIdx.x]     = s_sym[0] + s_sym[1] + s_sym[2] + s_sym[3];
        partial[2 * (size_t)blockIdx.x + 1] = s_proj[0] + s_proj[1] + s_proj[2] + s_proj[3];
    }
}

__global__ __launch_bounds__(256) void pose_calib_finish(
    const double* __restrict__ partial, int nblk,
    float* __restrict__ out, double inv_n_sym, double inv_n_proj)
{
    const double2* p2 = (const double2*)partial;
    double ss = 0.0, pp = 0.0;
    for (int i = threadIdx.x; i < nblk; i += 256) {
        double2 v = p2[i];
        ss += v.x;
        pp += v.y;
    }
    #pragma unroll
    for (int off = 32; off > 0; off >>= 1) {
        ss += __shfl_down(ss, off, 64);
        pp += __shfl_down(pp, off, 64);
    }
    __shared__ double s_s[4], s_p[4];
    const int lane = threadIdx.x & 63;
    const int wid  = threadIdx.x >> 6;
    if (lane == 0) { s_s[wid] = ss; s_p[wid] = pp; }
    __syncthreads();
    if (threadIdx.x == 0) {
        double S = s_s[0] + s_s[1] + s_s[2] + s_s[3];
        double P = s_p[0] + s_p[1] + s_p[2] + s_p[3];
        out[0] = (float)(S * inv_n_sym);
        out[1] = (float)(P * inv_n_proj);
    }
}

extern "C" void kernel_launch(void* const* d_in, const int* in_sizes, int n_in,
                              void* d_out, int out_size, void* d_ws, size_t ws_size,
                              hipStream_t stream) {
    const float* pose3d = (const float*)d_in[0];
    const float* pose2d = (const float*)d_in[1];
    const float* Rd     = (const float*)d_in[2];
    const float* Cd     = (const float*)d_in[3];

    const int B = in_sizes[3] / 3;                 // C_drone is (B,3,1)
    const int nblk = (B + 255) / 256;              // 1024 @ B=262144

    double* partial = (double*)d_ws;               // nblk*2 doubles (16 KB)

    pose_calib_main<<<nblk, 256, 0, stream>>>(pose3d, pose2d, Rd, Cd, partial, B);
    pose_calib_finish<<<1, 256, 0, stream>>>(
        partial, nblk, (float*)d_out,
        1.0 / ((double)B * 6.0), 1.0 / ((double)B * 30.0));
}